// Round 19
// baseline (42.744 us; speedup 1.0000x reference)
//
#include <hip/hip_runtime.h>

// GaussianAntecedent: out[n,r] = mem[n,r] / (sum_r mem[n,r] + 1e-8)
// mem = exp2( -sum_d clamp(q*(x-c), +-K)^2 ),  K = sqrt(-log2(1e-8))
//   q = sqrt(0.5*log2 e)/(sigma+eps)
//
// R18 post-mortem: rolling the loop regressed (I$ hypothesis dead).
// Cycle accounting on R16: 256 uniform ds_read_b128/wave x ~12cy on the
// SINGLE per-CU LDS pipe = ~15.6us of serialized constant service (half
// the runtime). R19: constants move to the SCALAR pipe (idle, own cache):
//  - setup kernel: [c[32]|q[32]] per rule into d_ws (16KB, K$-resident)
//  - r wave-uniform (readfirstlane) -> tr[d] compiles to batched s_loads
//  - inner ops each read <=1 SGPR (no marshaling movs -- R17's failure):
//      z = subrev(c_s, x_v); y = mul(q_s, z);
//      yc = med3(y, -K_s, K_s)  (same SGPR twice via neg-mod);
//      acc = fma(yc, -yc, acc)  (all-VGPR)
//  - LDS keeps only memL/partL/rsL (~36KB); R16 epilogue unchanged

constexpr int DDIM = 32;
constexpr int RR   = 64;
constexpr int ROWS = 128;         // rows per block (2 per lane)
constexpr int MP   = 130;         // mem tile pitch (floats)
constexpr int PP   = 5;           // partials pitch

__device__ inline float fast_exp2(float x) {
#if __has_builtin(__builtin_amdgcn_exp2f)
    return __builtin_amdgcn_exp2f(x);
#else
    return exp2f(x);
#endif
}

// ---- setup: per-rule table [ c[0..31] | q[0..31] ] (64 floats/rule) ----
__global__ void gauss_setup_kernel(const float* __restrict__ centers,
                                   const float* __restrict__ sigma,
                                   float* __restrict__ ws) {
    const float SQK = 0.84932180028801907f;   // sqrt(0.5 * log2(e))
    int idx = blockIdx.x * blockDim.x + threadIdx.x;
    if (idx < RR * DDIM) {
        int r = idx >> 5, d = idx & 31;
        ws[r * 64 + d]        = centers[r * DDIM + d];
        ws[r * 64 + DDIM + d] = SQK / (sigma[r * DDIM + d] + 1e-8f);
    }
}

__global__ __launch_bounds__(256, 3) void gauss_main(
    const float* __restrict__ X,
    const float* __restrict__ tab,    // d_ws: 64 rules x [c[32]|q[32]]
    float* __restrict__ out, int N)
{
    __shared__ float memL[RR * MP];       // 33.3 KB [rule][row]
    __shared__ float partL[ROWS * PP];    // 2.56 KB [row][wave]
    __shared__ float rsL[ROWS];           // 0.5 KB  rcp(S) per row

    const int tid  = threadIdx.x;
    const int lane = tid & 63;
    // wave index forced uniform so constant reads take the scalar path
    const int w    = __builtin_amdgcn_readfirstlane(tid >> 6);
    const int n0   = blockIdx.x * ROWS;

    // ---- own rows -> VGPRs (one coalesced load set per row) ----
    const int na = n0 + lane;
    const int nb = n0 + 64 + lane;
    const int ca = (na < N) ? na : (N - 1);
    const int cb = (nb < N) ? nb : (N - 1);
    const float4* __restrict__ xra =
        reinterpret_cast<const float4*>(X + (size_t)ca * DDIM);
    const float4* __restrict__ xrb =
        reinterpret_cast<const float4*>(X + (size_t)cb * DDIM);
    float xa[DDIM], xb[DDIM];
    #pragma unroll
    for (int j = 0; j < 8; ++j) {
        float4 va = xra[j], vb = xrb[j];
        xa[4*j+0] = va.x; xa[4*j+1] = va.y; xa[4*j+2] = va.z; xa[4*j+3] = va.w;
        xb[4*j+0] = vb.x; xb[4*j+1] = vb.y; xb[4*j+2] = vb.z; xb[4*j+3] = vb.w;
    }
    #pragma unroll
    for (int j = 0; j < DDIM; ++j) asm volatile("" : "+v"(xa[j]), "+v"(xb[j]));

    const float K = 5.1551357f;   // sqrt(26.575424759098897) = sqrt(-log2 1e-8)
    float Sa = 0.f, Sb = 0.f;

    // ---- 16 rules for this wave; constants via scalar s_loads ----
    #pragma unroll
    for (int rr = 0; rr < 16; ++rr) {
        const int r = w * 16 + rr;               // wave-uniform
        const float* __restrict__ tr = tab + r * 64;

        float A0 = 0.f, A1 = 0.f, A2 = 0.f, A3 = 0.f;
        float B0 = 0.f, B1 = 0.f, B2 = 0.f, B3 = 0.f;
        #pragma unroll
        for (int d = 0; d < DDIM; d += 4) {
            float c0 = tr[d+0], c1 = tr[d+1], c2 = tr[d+2], c3 = tr[d+3];
            float q0 = tr[DDIM+d+0], q1 = tr[DDIM+d+1];
            float q2 = tr[DDIM+d+2], q3 = tr[DDIM+d+3];
            float ya0 = (xa[d+0] - c0) * q0;
            float ya1 = (xa[d+1] - c1) * q1;
            float ya2 = (xa[d+2] - c2) * q2;
            float ya3 = (xa[d+3] - c3) * q3;
            float yb0 = (xb[d+0] - c0) * q0;
            float yb1 = (xb[d+1] - c1) * q1;
            float yb2 = (xb[d+2] - c2) * q2;
            float yb3 = (xb[d+3] - c3) * q3;
            ya0 = fminf(fmaxf(ya0, -K), K); ya1 = fminf(fmaxf(ya1, -K), K);
            ya2 = fminf(fmaxf(ya2, -K), K); ya3 = fminf(fmaxf(ya3, -K), K);
            yb0 = fminf(fmaxf(yb0, -K), K); yb1 = fminf(fmaxf(yb1, -K), K);
            yb2 = fminf(fmaxf(yb2, -K), K); yb3 = fminf(fmaxf(yb3, -K), K);
            A0 = fmaf(ya0, -ya0, A0); A1 = fmaf(ya1, -ya1, A1);
            A2 = fmaf(ya2, -ya2, A2); A3 = fmaf(ya3, -ya3, A3);
            B0 = fmaf(yb0, -yb0, B0); B1 = fmaf(yb1, -yb1, B1);
            B2 = fmaf(yb2, -yb2, B2); B3 = fmaf(yb3, -yb3, B3);
        }
        float ma = fast_exp2((A0 + A1) + (A2 + A3));
        float mb = fast_exp2((B0 + B1) + (B2 + B3));
        Sa += ma;
        Sb += mb;
        memL[r * MP + lane]      = ma;   // stride-1 across lanes: clean
        memL[r * MP + 64 + lane] = mb;
    }
    partL[lane * PP + w]        = Sa;    // (5*lane+w)%32: 2-way, free
    partL[(64 + lane) * PP + w] = Sb;

    __syncthreads();   // mem tile + partials ready

    if (tid < ROWS) {
        float s = partL[tid * PP + 0] + partL[tid * PP + 1] +
                  partL[tid * PP + 2] + partL[tid * PP + 3];
        rsL[tid] = __builtin_amdgcn_rcpf(s + 1e-8f);
    }
    __syncthreads();   // rs ready

    // ---- epilogue: contiguous 4KB-per-step float4 stores ----
    const int nvalid = N - n0;   // rows in this block (128 except last)
    #pragma unroll
    for (int ch = 0; ch < 8; ++ch) {
        const int f4  = ch * 256 + tid;       // 0..2047
        const int row = f4 >> 4;              // 0..127
        const int r4  = (f4 & 15) * 4;        // rule quad base
        if (row < nvalid) {
            float rs = rsL[row];
            float4 o;
            o.x = memL[(r4 + 0) * MP + row] * rs;
            o.y = memL[(r4 + 1) * MP + row] * rs;
            o.z = memL[(r4 + 2) * MP + row] * rs;
            o.w = memL[(r4 + 3) * MP + row] * rs;
            *reinterpret_cast<float4*>(&out[(size_t)(n0 + row) * RR + r4]) = o;
        }
    }
}

extern "C" void kernel_launch(void* const* d_in, const int* in_sizes, int n_in,
                              void* d_out, int out_size, void* d_ws, size_t ws_size,
                              hipStream_t stream) {
    const float* X       = (const float*)d_in[0];
    const float* centers = (const float*)d_in[1];
    const float* sigma   = (const float*)d_in[2];
    float* out = (float*)d_out;
    float* ws  = (float*)d_ws;   // needs 64*64*4 = 16 KB

    const int N = in_sizes[0] / DDIM;  // 100000

    // 1) build per-rule c/q table (2048 elems)
    gauss_setup_kernel<<<8, 256, 0, stream>>>(centers, sigma, ws);

    // 2) main: 782 blocks x 256 threads (128 rows/block, rules split 4 ways)
    const int grid = (N + ROWS - 1) / ROWS;   // 782
    gauss_main<<<grid, 256, 0, stream>>>(X, ws, out, N);
}